// Round 1
// baseline (255.352 us; speedup 1.0000x reference)
//
#include <hip/hip_runtime.h>

// Shapes: B=32, S_NEW=1, DIM=4096, H=32, KV=8, HD=128, PREV=2048, SEQ=2049
// All inputs/outputs fp32.
//
// ws layout (float offsets):
//   P1   [16][32][6144] @ 0        (3145728 floats) qkv split-K partials
//   qkv  [32][6144]     @ 3145728  (196608)  rope'd q (scaled), k_new, v_new
//   attn [32][4096]     @ 3342336  (131072)  attention output (b, h, d)
//   P2   [16][32][4096] @ 3473408  (2097152) out-proj split-K partials

#define WS_P1   0
#define WS_QKV  3145728
#define WS_ATTN 3342336
#define WS_P2   3473408

// ---------------------------------------------------------------------------
// Skinny GEMM partial: P[ks][b][n] = sum_{k in 256-chunk} X[b][k] * W[k][n]
// grid: (Ntot/256, 16), block: 256 threads = 128 colpairs x 2 k-groups.
// X is [32][4096] (row stride 4096). Up to 3 weight segments (for QKV).
// ---------------------------------------------------------------------------
__global__ __launch_bounds__(256) void gemm_skinny(
    const float* __restrict__ X,
    const float* __restrict__ W0, int e0, int ld0,
    const float* __restrict__ W1, int e1, int ld1,
    const float* __restrict__ W2, int ld2,
    float* __restrict__ P, int Ntot)
{
    __shared__ float x_t[128][36];     // transposed x chunk [kk][b], pad 36
    __shared__ float2 red[128][33];    // 2-way kg reduce, pad 33

    const int nb = blockIdx.x * 256;
    const float* W; int ld, noff;
    if (nb < e0)      { W = W0; ld = ld0; noff = 0;  }
    else if (nb < e1) { W = W1; ld = ld1; noff = e0; }
    else              { W = W2; ld = ld2; noff = e1; }

    const int k0  = blockIdx.y * 256;
    const int tid = threadIdx.x;
    const int cp  = tid & 127;      // colpair 0..127
    const int kg  = tid >> 7;       // 0..1
    const int nn  = nb - noff + cp * 2;

    float2 acc[32];
    #pragma unroll
    for (int b = 0; b < 32; ++b) { acc[b].x = 0.f; acc[b].y = 0.f; }

    for (int c = 0; c < 2; ++c) {
        __syncthreads();
        // stage x[32][128] transposed, coalesced global reads
        #pragma unroll
        for (int i = 0; i < 16; ++i) {
            int idx = tid + i * 256;
            int bb = idx >> 7, kk = idx & 127;
            x_t[kk][bb] = X[(size_t)bb * 4096 + k0 + c * 128 + kk];
        }
        __syncthreads();

        const float* Wp = W + (size_t)(k0 + c * 128) * ld + nn;
        for (int kk = kg * 64; kk < kg * 64 + 64; ++kk) {
            float2 w2 = *(const float2*)&Wp[(size_t)kk * ld];
            const float* xr = x_t[kk];
            #pragma unroll
            for (int bq = 0; bq < 8; ++bq) {
                float4 xv = *(const float4*)&xr[bq * 4];
                acc[bq*4+0].x += xv.x * w2.x; acc[bq*4+0].y += xv.x * w2.y;
                acc[bq*4+1].x += xv.y * w2.x; acc[bq*4+1].y += xv.y * w2.y;
                acc[bq*4+2].x += xv.z * w2.x; acc[bq*4+2].y += xv.z * w2.y;
                acc[bq*4+3].x += xv.w * w2.x; acc[bq*4+3].y += xv.w * w2.y;
            }
        }
    }

    if (kg == 1) {
        #pragma unroll
        for (int b = 0; b < 32; ++b) red[cp][b] = acc[b];
    }
    __syncthreads();
    if (kg == 0) {
        const int ks = blockIdx.y;
        #pragma unroll
        for (int b = 0; b < 32; ++b) {
            float2 o = red[cp][b];
            float2 v; v.x = acc[b].x + o.x; v.y = acc[b].y + o.y;
            *(float2*)&P[((size_t)ks * 32 + b) * Ntot + nb + cp * 2] = v;
        }
    }
}

// ---------------------------------------------------------------------------
// Reduce 16 split-K partials for QKV + fused RoPE (+ 1/sqrt(128) on q).
// grid 384 x 256; each thread owns one (b, colpair).
// ---------------------------------------------------------------------------
__global__ __launch_bounds__(256) void reduce_rope(
    const float* __restrict__ P, const float* __restrict__ freqs,
    float* __restrict__ qkv)
{
    int t = blockIdx.x * 256 + threadIdx.x;   // 0..98303
    int b = t / 3072;
    int cp = t - b * 3072;
    int n = cp * 2;
    float sx = 0.f, sy = 0.f;
    #pragma unroll
    for (int ks = 0; ks < 16; ++ks) {
        float2 v = *(const float2*)&P[((size_t)ks * 32 + b) * 6144 + n];
        sx += v.x; sy += v.y;
    }
    if (n < 5120) {  // rope on q and k
        int d = n & 127;
        float fr = freqs[d >> 1];
        float c = cosf(fr), s = sinf(fr);
        float ra = sx * c - sy * s;
        float rb = sx * s + sy * c;
        if (n < 4096) {  // fold score scale into q
            const float sc = 0.08838834764831845f;  // 1/sqrt(128)
            ra *= sc; rb *= sc;
        }
        sx = ra; sy = rb;
    }
    float2 o; o.x = sx; o.y = sy;
    *(float2*)&qkv[(size_t)b * 6144 + n] = o;
}

// ---------------------------------------------------------------------------
// Attention: one block per (b, kv). 1024 threads.
// Phase1: scores[4][2049]; softmax; Phase2: out[4][128].
// ---------------------------------------------------------------------------
__global__ __launch_bounds__(1024) void attn_kernel(
    const float* __restrict__ qkv,
    const float* __restrict__ ck, const float* __restrict__ cv,
    float* __restrict__ ao)
{
    // sbuf aliases: phase1/softmax: sc[h][s] = sbuf[h*2052+s] (8208 floats)
    //               final reduce:   op[w][j] = sbuf[w*512+j]  (8192 floats)
    __shared__ float sbuf[8208];
    __shared__ float red[4][4];
    __shared__ float mxv[4];
    __shared__ float inv[4];

    const int b  = blockIdx.x >> 3;
    const int kv = blockIdx.x & 7;
    const int tid = threadIdx.x;
    const int wave = tid >> 6, lane = tid & 63;
    const int psub = (lane >> 4) & 3, dl = lane & 15;

    // q fragments: 4 heads x 8 dims (this lane's d-slice), already scaled
    float q[4][8];
    {
        const float* qb = qkv + (size_t)b * 6144 + kv * 512 + dl * 8;
        #pragma unroll
        for (int h = 0; h < 4; ++h) {
            float4 a = *(const float4*)&qb[h * 128];
            float4 c = *(const float4*)&qb[h * 128 + 4];
            q[h][0]=a.x; q[h][1]=a.y; q[h][2]=a.z; q[h][3]=a.w;
            q[h][4]=c.x; q[h][5]=c.y; q[h][6]=c.z; q[h][7]=c.w;
        }
    }

    // -------- phase 1: scores --------
    const float* kbase = ck + ((size_t)b * 2048 * 8 + kv) * 128;
    for (int it = 0; it < 33; ++it) {
        int s = it * 64 + wave * 4 + psub;
        if (s <= 2048) {
            const float* kr = (s < 2048)
                ? (kbase + (size_t)s * 1024)
                : (qkv + (size_t)b * 6144 + 4096 + kv * 128);
            float4 k0 = *(const float4*)&kr[dl * 8];
            float4 k1 = *(const float4*)&kr[dl * 8 + 4];
            float p[4];
            #pragma unroll
            for (int h = 0; h < 4; ++h) {
                p[h] = q[h][0]*k0.x + q[h][1]*k0.y + q[h][2]*k0.z + q[h][3]*k0.w
                     + q[h][4]*k1.x + q[h][5]*k1.y + q[h][6]*k1.z + q[h][7]*k1.w;
            }
            #pragma unroll
            for (int off = 1; off < 16; off <<= 1) {
                #pragma unroll
                for (int h = 0; h < 4; ++h) p[h] += __shfl_xor(p[h], off);
            }
            if (dl == 0) {
                #pragma unroll
                for (int h = 0; h < 4; ++h) sbuf[h * 2052 + s] = p[h];
            }
        }
    }
    __syncthreads();

    // -------- softmax (per head; 256 threads per head) --------
    const int h = tid >> 8, r = tid & 255;
    float m = -1e30f;
    for (int s = r; s < 2049; s += 256) m = fmaxf(m, sbuf[h * 2052 + s]);
    #pragma unroll
    for (int off = 1; off < 64; off <<= 1) m = fmaxf(m, __shfl_xor(m, off));
    if (lane == 0) red[h][wave & 3] = m;
    __syncthreads();
    if (r == 0)
        mxv[h] = fmaxf(fmaxf(red[h][0], red[h][1]), fmaxf(red[h][2], red[h][3]));
    __syncthreads();
    const float mx = mxv[h];
    float sum = 0.f;
    for (int s = r; s < 2049; s += 256) {
        float p = __expf(sbuf[h * 2052 + s] - mx);
        sbuf[h * 2052 + s] = p;
        sum += p;
    }
    #pragma unroll
    for (int off = 1; off < 64; off <<= 1) sum += __shfl_xor(sum, off);
    if (lane == 0) red[h][wave & 3] = sum;
    __syncthreads();
    if (r == 0) inv[h] = 1.0f / (red[h][0] + red[h][1] + red[h][2] + red[h][3]);
    __syncthreads();

    // -------- phase 2: out = P @ V (V read once, all 4 heads) --------
    const int grp = tid >> 5, l32 = tid & 31, d4 = l32 * 4;
    float4 acc[4];
    #pragma unroll
    for (int hh = 0; hh < 4; ++hh) { acc[hh].x=0.f; acc[hh].y=0.f; acc[hh].z=0.f; acc[hh].w=0.f; }
    const float* vbase = cv + ((size_t)b * 2048 * 8 + kv) * 128;
    for (int s = grp; s < 2049; s += 32) {
        const float* vr = (s < 2048)
            ? (vbase + (size_t)s * 1024)
            : (qkv + (size_t)b * 6144 + 5120 + kv * 128);
        float4 v = *(const float4*)&vr[d4];
        #pragma unroll
        for (int hh = 0; hh < 4; ++hh) {
            float p = sbuf[hh * 2052 + s];
            acc[hh].x += p * v.x; acc[hh].y += p * v.y;
            acc[hh].z += p * v.z; acc[hh].w += p * v.w;
        }
    }
    __syncthreads();   // done reading sc region; sbuf becomes op[16][512]

    // combine wave halves (groups 2w and 2w+1) via shfl
    #pragma unroll
    for (int hh = 0; hh < 4; ++hh) {
        acc[hh].x += __shfl_down(acc[hh].x, 32);
        acc[hh].y += __shfl_down(acc[hh].y, 32);
        acc[hh].z += __shfl_down(acc[hh].z, 32);
        acc[hh].w += __shfl_down(acc[hh].w, 32);
    }
    if (l32 == (lane & 31) && lane < 32) {
        #pragma unroll
        for (int hh = 0; hh < 4; ++hh)
            *(float4*)&sbuf[wave * 512 + hh * 128 + d4] = acc[hh];
    }
    __syncthreads();

    if (tid < 512) {
        int hh = tid >> 7, d = tid & 127;
        float v = 0.f;
        #pragma unroll
        for (int w = 0; w < 16; ++w) v += sbuf[w * 512 + hh * 128 + d];
        ao[(size_t)b * 4096 + kv * 512 + hh * 128 + d] = v * inv[hh];
    }
}

// ---------------------------------------------------------------------------
// Reduce 16 split-K partials for output projection -> d_out
// ---------------------------------------------------------------------------
__global__ __launch_bounds__(256) void reduce_out(
    const float* __restrict__ P, float* __restrict__ out)
{
    int t = blockIdx.x * 256 + threadIdx.x;   // 0..65535 (float2 units)
    int b = t >> 11;            // /2048
    int cp = t & 2047;
    int n = cp * 2;
    float sx = 0.f, sy = 0.f;
    #pragma unroll
    for (int ks = 0; ks < 16; ++ks) {
        float2 v = *(const float2*)&P[((size_t)ks * 32 + b) * 4096 + n];
        sx += v.x; sy += v.y;
    }
    float2 o; o.x = sx; o.y = sy;
    *(float2*)&out[(size_t)b * 4096 + n] = o;
}

extern "C" void kernel_launch(void* const* d_in, const int* in_sizes, int n_in,
                              void* d_out, int out_size, void* d_ws, size_t ws_size,
                              hipStream_t stream) {
    const float* x  = (const float*)d_in[0];
    const float* wq = (const float*)d_in[1];
    const float* wk = (const float*)d_in[2];
    const float* wv = (const float*)d_in[3];
    const float* wo = (const float*)d_in[4];
    const float* ck = (const float*)d_in[5];
    const float* cv = (const float*)d_in[6];
    const float* fr = (const float*)d_in[7];
    float* out = (float*)d_out;
    float* ws  = (float*)d_ws;

    float* P1   = ws + WS_P1;
    float* qkv  = ws + WS_QKV;
    float* attn = ws + WS_ATTN;
    float* P2   = ws + WS_P2;

    // 1) QKV projection partials
    dim3 g1(24, 16);
    gemm_skinny<<<g1, 256, 0, stream>>>(x, wq, 4096, 4096, wk, 5120, 1024,
                                        wv, 1024, P1, 6144);
    // 2) reduce + RoPE
    reduce_rope<<<384, 256, 0, stream>>>(P1, fr, qkv);
    // 3) attention
    attn_kernel<<<256, 1024, 0, stream>>>(qkv, ck, cv, attn);
    // 4) output projection partials
    dim3 g4(16, 16);
    gemm_skinny<<<g4, 256, 0, stream>>>(attn, wo, 4096, 4096, wo, 4096, 4096,
                                        wo, 4096, P2, 4096);
    // 5) reduce -> out
    reduce_out<<<256, 256, 0, stream>>>(P2, out);
}

// Round 2
// 254.613 us; speedup vs baseline: 1.0029x; 1.0029x over previous
//
#include <hip/hip_runtime.h>

// Shapes: B=32, S_NEW=1, DIM=4096, H=32, KV=8, HD=128, PREV=2048, SEQ=2049
// All inputs/outputs fp32.
//
// ws layout (float offsets):
//   P1   [16][32][6144] @ 0        (3145728 floats) qkv split-K partials
//   qkv  [32][6144]     @ 3145728  (196608)  rope'd q (scaled), k_new, v_new
//   attn [32][4096]     @ 3342336  (131072)  attention output (b, h, d)
//   P2   [16][32][4096] @ 3473408  (2097152) out-proj split-K partials

#define WS_P1   0
#define WS_QKV  3145728
#define WS_ATTN 3342336
#define WS_P2   3473408

// ---------------------------------------------------------------------------
// Skinny GEMM partial: P[ks][b][n] = sum_{k in 256-chunk} X[b][k] * W[k][n]
// grid: (Ntot/256, 16), block: 256 threads = 128 colpairs x 2 k-groups.
// ---------------------------------------------------------------------------
__global__ __launch_bounds__(256) void gemm_skinny(
    const float* __restrict__ X,
    const float* __restrict__ W0, int e0, int ld0,
    const float* __restrict__ W1, int e1, int ld1,
    const float* __restrict__ W2, int ld2,
    float* __restrict__ P, int Ntot)
{
    __shared__ float x_t[128][36];     // transposed x chunk [kk][b], pad 36
    __shared__ float2 red[128][33];    // 2-way kg reduce, pad 33

    const int nb = blockIdx.x * 256;
    const float* W; int ld, noff;
    if (nb < e0)      { W = W0; ld = ld0; noff = 0;  }
    else if (nb < e1) { W = W1; ld = ld1; noff = e0; }
    else              { W = W2; ld = ld2; noff = e1; }

    const int k0  = blockIdx.y * 256;
    const int tid = threadIdx.x;
    const int cp  = tid & 127;      // colpair 0..127
    const int kg  = tid >> 7;       // 0..1
    const int nn  = nb - noff + cp * 2;

    float2 acc[32];
    #pragma unroll
    for (int b = 0; b < 32; ++b) { acc[b].x = 0.f; acc[b].y = 0.f; }

    for (int c = 0; c < 2; ++c) {
        __syncthreads();
        #pragma unroll
        for (int i = 0; i < 16; ++i) {
            int idx = tid + i * 256;
            int bb = idx >> 7, kk = idx & 127;
            x_t[kk][bb] = X[(size_t)bb * 4096 + k0 + c * 128 + kk];
        }
        __syncthreads();

        const float* Wp = W + (size_t)(k0 + c * 128) * ld + nn;
        for (int kk = kg * 64; kk < kg * 64 + 64; ++kk) {
            float2 w2 = *(const float2*)&Wp[(size_t)kk * ld];
            const float* xr = x_t[kk];
            #pragma unroll
            for (int bq = 0; bq < 8; ++bq) {
                float4 xv = *(const float4*)&xr[bq * 4];
                acc[bq*4+0].x += xv.x * w2.x; acc[bq*4+0].y += xv.x * w2.y;
                acc[bq*4+1].x += xv.y * w2.x; acc[bq*4+1].y += xv.y * w2.y;
                acc[bq*4+2].x += xv.z * w2.x; acc[bq*4+2].y += xv.z * w2.y;
                acc[bq*4+3].x += xv.w * w2.x; acc[bq*4+3].y += xv.w * w2.y;
            }
        }
    }

    if (kg == 1) {
        #pragma unroll
        for (int b = 0; b < 32; ++b) red[cp][b] = acc[b];
    }
    __syncthreads();
    if (kg == 0) {
        const int ks = blockIdx.y;
        #pragma unroll
        for (int b = 0; b < 32; ++b) {
            float2 o = red[cp][b];
            float2 v; v.x = acc[b].x + o.x; v.y = acc[b].y + o.y;
            *(float2*)&P[((size_t)ks * 32 + b) * Ntot + nb + cp * 2] = v;
        }
    }
}

// ---------------------------------------------------------------------------
// Reduce 16 split-K partials for QKV + fused RoPE (+ 1/sqrt(128) on q).
// ---------------------------------------------------------------------------
__global__ __launch_bounds__(256) void reduce_rope(
    const float* __restrict__ P, const float* __restrict__ freqs,
    float* __restrict__ qkv)
{
    int t = blockIdx.x * 256 + threadIdx.x;   // 0..98303
    int b = t / 3072;
    int cp = t - b * 3072;
    int n = cp * 2;
    float sx = 0.f, sy = 0.f;
    #pragma unroll
    for (int ks = 0; ks < 16; ++ks) {
        float2 v = *(const float2*)&P[((size_t)ks * 32 + b) * 6144 + n];
        sx += v.x; sy += v.y;
    }
    if (n < 5120) {
        int d = n & 127;
        float fr = freqs[d >> 1];
        float c = cosf(fr), s = sinf(fr);
        float ra = sx * c - sy * s;
        float rb = sx * s + sy * c;
        if (n < 4096) {
            const float sc = 0.08838834764831845f;  // 1/sqrt(128)
            ra *= sc; rb *= sc;
        }
        sx = ra; sy = rb;
    }
    float2 o; o.x = sx; o.y = sy;
    *(float2*)&qkv[(size_t)b * 6144 + n] = o;
}

// ---------------------------------------------------------------------------
// Attention: one block per (b, kv). 1024 threads.
// Phase1 (4-deep batched loads): scores[4][2049]; softmax; Phase2 (batched).
// ---------------------------------------------------------------------------
__global__ __launch_bounds__(1024) void attn_kernel(
    const float* __restrict__ qkv,
    const float* __restrict__ ck, const float* __restrict__ cv,
    float* __restrict__ ao)
{
    // sbuf aliases: scores sc[h][s] = sbuf[h*2052+s] (8208 floats)
    //               final reduce:   op[w][j] = sbuf[w*512+j] (8192 floats)
    __shared__ float sbuf[8208];
    __shared__ float red[4][4];
    __shared__ float mxv[4];
    __shared__ float inv[4];

    const int b  = blockIdx.x >> 3;
    const int kv = blockIdx.x & 7;
    const int tid = threadIdx.x;
    const int wave = tid >> 6, lane = tid & 63;
    const int psub = (lane >> 4) & 3, dl = lane & 15;

    // q fragments: 4 heads x this lane's 8-dim slice, pre-scaled by 1/sqrt(128)
    float q[4][8];
    {
        const float* qb = qkv + (size_t)b * 6144 + kv * 512 + dl * 8;
        #pragma unroll
        for (int h = 0; h < 4; ++h) {
            float4 a = *(const float4*)&qb[h * 128];
            float4 c = *(const float4*)&qb[h * 128 + 4];
            q[h][0]=a.x; q[h][1]=a.y; q[h][2]=a.z; q[h][3]=a.w;
            q[h][4]=c.x; q[h][5]=c.y; q[h][6]=c.z; q[h][7]=c.w;
        }
    }

    // -------- new-token score (s == 2048), lanes 0..15 of wave 0 --------
    if (tid < 16) {
        const float* kr = qkv + (size_t)b * 6144 + 4096 + kv * 128 + dl * 8;
        float4 k0 = *(const float4*)kr;
        float4 k1 = *(const float4*)(kr + 4);
        float p[4];
        #pragma unroll
        for (int h = 0; h < 4; ++h) {
            p[h] = q[h][0]*k0.x + q[h][1]*k0.y + q[h][2]*k0.z + q[h][3]*k0.w
                 + q[h][4]*k1.x + q[h][5]*k1.y + q[h][6]*k1.z + q[h][7]*k1.w;
        }
        #pragma unroll
        for (int off = 1; off < 16; off <<= 1) {
            #pragma unroll
            for (int h = 0; h < 4; ++h) p[h] += __shfl_xor(p[h], off);
        }
        if (dl == 0) {
            #pragma unroll
            for (int h = 0; h < 4; ++h) sbuf[h * 2052 + 2048] = p[h];
        }
    }

    // -------- phase 1: scores for rows 0..2047, 4-deep load batching --------
    const float* kbase = ck + ((size_t)b * 2048 * 8 + kv) * 128;
    const int srow = wave * 4 + psub;        // 0..63 within each 64-row group
    for (int it0 = 0; it0 < 32; it0 += 4) {
        float4 kA[4][2];
        #pragma unroll
        for (int u = 0; u < 4; ++u) {
            const float* kr = kbase + (size_t)((it0 + u) * 64 + srow) * 1024 + dl * 8;
            kA[u][0] = *(const float4*)kr;
            kA[u][1] = *(const float4*)(kr + 4);
        }
        #pragma unroll
        for (int u = 0; u < 4; ++u) {
            int s = (it0 + u) * 64 + srow;
            float p[4];
            #pragma unroll
            for (int h = 0; h < 4; ++h) {
                p[h] = q[h][0]*kA[u][0].x + q[h][1]*kA[u][0].y
                     + q[h][2]*kA[u][0].z + q[h][3]*kA[u][0].w
                     + q[h][4]*kA[u][1].x + q[h][5]*kA[u][1].y
                     + q[h][6]*kA[u][1].z + q[h][7]*kA[u][1].w;
            }
            #pragma unroll
            for (int off = 1; off < 16; off <<= 1) {
                #pragma unroll
                for (int h = 0; h < 4; ++h) p[h] += __shfl_xor(p[h], off);
            }
            if (dl == 0) {
                #pragma unroll
                for (int h = 0; h < 4; ++h) sbuf[h * 2052 + s] = p[h];
            }
        }
    }
    __syncthreads();

    // -------- softmax (per head; 256 threads per head) --------
    const int h = tid >> 8, r = tid & 255;
    float m = -1e30f;
    for (int s = r; s < 2049; s += 256) m = fmaxf(m, sbuf[h * 2052 + s]);
    #pragma unroll
    for (int off = 1; off < 64; off <<= 1) m = fmaxf(m, __shfl_xor(m, off));
    if (lane == 0) red[h][wave & 3] = m;
    __syncthreads();
    if (r == 0)
        mxv[h] = fmaxf(fmaxf(red[h][0], red[h][1]), fmaxf(red[h][2], red[h][3]));
    __syncthreads();
    const float mx = mxv[h];
    float sum = 0.f;
    for (int s = r; s < 2049; s += 256) {
        float p = __expf(sbuf[h * 2052 + s] - mx);
        sbuf[h * 2052 + s] = p;
        sum += p;
    }
    #pragma unroll
    for (int off = 1; off < 64; off <<= 1) sum += __shfl_xor(sum, off);
    if (lane == 0) red[h][wave & 3] = sum;
    __syncthreads();
    if (r == 0) inv[h] = 1.0f / (red[h][0] + red[h][1] + red[h][2] + red[h][3]);
    __syncthreads();

    // -------- phase 2: out = P @ V, 4-deep load batching --------
    const int grp = tid >> 5, l32 = tid & 31, d4 = l32 * 4;
    float4 acc[4];
    #pragma unroll
    for (int hh = 0; hh < 4; ++hh) { acc[hh].x=0.f; acc[hh].y=0.f; acc[hh].z=0.f; acc[hh].w=0.f; }
    const float* vbase = cv + ((size_t)b * 2048 * 8 + kv) * 128;
    for (int it = 0; it < 16; ++it) {
        float4 vv[4];
        float pp[4][4];
        #pragma unroll
        for (int j = 0; j < 4; ++j) {
            int s = it * 128 + j * 32 + grp;
            vv[j] = *(const float4*)&vbase[(size_t)s * 1024 + d4];
        }
        #pragma unroll
        for (int j = 0; j < 4; ++j) {
            int s = it * 128 + j * 32 + grp;
            #pragma unroll
            for (int hh = 0; hh < 4; ++hh) pp[j][hh] = sbuf[hh * 2052 + s];
        }
        #pragma unroll
        for (int j = 0; j < 4; ++j) {
            #pragma unroll
            for (int hh = 0; hh < 4; ++hh) {
                acc[hh].x += pp[j][hh] * vv[j].x;
                acc[hh].y += pp[j][hh] * vv[j].y;
                acc[hh].z += pp[j][hh] * vv[j].z;
                acc[hh].w += pp[j][hh] * vv[j].w;
            }
        }
    }
    // new token s = 2048: group 0 only (lanes 0..31 of wave 0)
    if (grp == 0) {
        const float* vr = qkv + (size_t)b * 6144 + 5120 + kv * 128;
        float4 v = *(const float4*)&vr[d4];
        #pragma unroll
        for (int hh = 0; hh < 4; ++hh) {
            float p = sbuf[hh * 2052 + 2048];
            acc[hh].x += p * v.x; acc[hh].y += p * v.y;
            acc[hh].z += p * v.z; acc[hh].w += p * v.w;
        }
    }
    __syncthreads();   // sc region done; sbuf becomes op[16][512]

    #pragma unroll
    for (int hh = 0; hh < 4; ++hh) {
        acc[hh].x += __shfl_down(acc[hh].x, 32);
        acc[hh].y += __shfl_down(acc[hh].y, 32);
        acc[hh].z += __shfl_down(acc[hh].z, 32);
        acc[hh].w += __shfl_down(acc[hh].w, 32);
    }
    if (lane < 32) {
        #pragma unroll
        for (int hh = 0; hh < 4; ++hh)
            *(float4*)&sbuf[wave * 512 + hh * 128 + d4] = acc[hh];
    }
    __syncthreads();

    if (tid < 512) {
        int hh = tid >> 7, d = tid & 127;
        float v = 0.f;
        #pragma unroll
        for (int w = 0; w < 16; ++w) v += sbuf[w * 512 + hh * 128 + d];
        ao[(size_t)b * 4096 + kv * 512 + hh * 128 + d] = v * inv[hh];
    }
}

// ---------------------------------------------------------------------------
// Reduce 16 split-K partials for output projection -> d_out
// ---------------------------------------------------------------------------
__global__ __launch_bounds__(256) void reduce_out(
    const float* __restrict__ P, float* __restrict__ out)
{
    int t = blockIdx.x * 256 + threadIdx.x;   // float2 units
    int b = t >> 11;
    int cp = t & 2047;
    int n = cp * 2;
    float sx = 0.f, sy = 0.f;
    #pragma unroll
    for (int ks = 0; ks < 16; ++ks) {
        float2 v = *(const float2*)&P[((size_t)ks * 32 + b) * 4096 + n];
        sx += v.x; sy += v.y;
    }
    float2 o; o.x = sx; o.y = sy;
    *(float2*)&out[(size_t)b * 4096 + n] = o;
}

extern "C" void kernel_launch(void* const* d_in, const int* in_sizes, int n_in,
                              void* d_out, int out_size, void* d_ws, size_t ws_size,
                              hipStream_t stream) {
    const float* x  = (const float*)d_in[0];
    const float* wq = (const float*)d_in[1];
    const float* wk = (const float*)d_in[2];
    const float* wv = (const float*)d_in[3];
    const float* wo = (const float*)d_in[4];
    const float* ck = (const float*)d_in[5];
    const float* cv = (const float*)d_in[6];
    const float* fr = (const float*)d_in[7];
    float* out = (float*)d_out;
    float* ws  = (float*)d_ws;

    float* P1   = ws + WS_P1;
    float* qkv  = ws + WS_QKV;
    float* attn = ws + WS_ATTN;
    float* P2   = ws + WS_P2;

    dim3 g1(24, 16);
    gemm_skinny<<<g1, 256, 0, stream>>>(x, wq, 4096, 4096, wk, 5120, 1024,
                                        wv, 1024, P1, 6144);
    reduce_rope<<<384, 256, 0, stream>>>(P1, fr, qkv);
    attn_kernel<<<256, 1024, 0, stream>>>(qkv, ck, cv, attn);
    dim3 g4(16, 16);
    gemm_skinny<<<g4, 256, 0, stream>>>(attn, wo, 4096, 4096, wo, 4096, 4096,
                                        wo, 4096, P2, 4096);
    reduce_out<<<256, 256, 0, stream>>>(P2, out);
}

// Round 3
// 183.694 us; speedup vs baseline: 1.3901x; 1.3861x over previous
//
#include <hip/hip_runtime.h>

// Shapes: B=32, S_NEW=1, DIM=4096, H=32, KV=8, HD=128, PREV=2048, SEQ=2049
// All inputs/outputs fp32.
//
// ws layout (float offsets):
//   P1   [32][32][6144] @ 0        (6291456 floats) qkv split-K partials
//   qkv  [32][6144]     @ 6291456  (196608)  rope'd q (scaled), k_new, v_new
//   attn [32][4096]     @ 6488064  (131072)  attention output (b, h, d)
//   P2   [32][32][4096] @ 6619136  (4194304) out-proj split-K partials

#define WS_P1   0
#define WS_QKV  6291456
#define WS_ATTN 6488064
#define WS_P2   6619136

// ---------------------------------------------------------------------------
// Skinny GEMM partial: P[ks][b][n] = sum_{k in 128-chunk} X[b][k] * W[k][n]
// grid: (Ntot/256, 32), block: 256 threads = 128 colpairs x 2 k-groups.
// 8-deep explicit weight prefetch to tolerate HBM latency at low occupancy.
// ---------------------------------------------------------------------------
__global__ __launch_bounds__(256) void gemm_skinny(
    const float* __restrict__ X,
    const float* __restrict__ W0, int e0, int ld0,
    const float* __restrict__ W1, int e1, int ld1,
    const float* __restrict__ W2, int ld2,
    float* __restrict__ P, int Ntot)
{
    __shared__ float x_t[128][36];     // transposed x chunk [kk][b], pad 36
    __shared__ float2 red[128][33];    // 2-way kg reduce, pad 33

    const int nb = blockIdx.x * 256;
    const float* W; int ld, noff;
    if (nb < e0)      { W = W0; ld = ld0; noff = 0;  }
    else if (nb < e1) { W = W1; ld = ld1; noff = e0; }
    else              { W = W2; ld = ld2; noff = e1; }

    const int k0  = blockIdx.y * 128;
    const int tid = threadIdx.x;
    const int cp  = tid & 127;      // colpair 0..127
    const int kg  = tid >> 7;       // 0..1
    const int nn  = nb - noff + cp * 2;

    // stage x[32][128] transposed, coalesced global reads
    #pragma unroll
    for (int i = 0; i < 16; ++i) {
        int idx = tid + i * 256;
        int bb = idx >> 7, kk = idx & 127;
        x_t[kk][bb] = X[(size_t)bb * 4096 + k0 + kk];
    }
    __syncthreads();

    float2 acc[32];
    #pragma unroll
    for (int b = 0; b < 32; ++b) { acc[b].x = 0.f; acc[b].y = 0.f; }

    const float* Wp = W + (size_t)k0 * ld + nn;
    for (int kk0 = kg * 64; kk0 < kg * 64 + 64; kk0 += 8) {
        float2 w[8];
        #pragma unroll
        for (int u = 0; u < 8; ++u)
            w[u] = *(const float2*)&Wp[(size_t)(kk0 + u) * ld];
        #pragma unroll
        for (int u = 0; u < 8; ++u) {
            const float* xr = x_t[kk0 + u];
            #pragma unroll
            for (int bq = 0; bq < 8; ++bq) {
                float4 xv = *(const float4*)&xr[bq * 4];
                acc[bq*4+0].x += xv.x * w[u].x; acc[bq*4+0].y += xv.x * w[u].y;
                acc[bq*4+1].x += xv.y * w[u].x; acc[bq*4+1].y += xv.y * w[u].y;
                acc[bq*4+2].x += xv.z * w[u].x; acc[bq*4+2].y += xv.z * w[u].y;
                acc[bq*4+3].x += xv.w * w[u].x; acc[bq*4+3].y += xv.w * w[u].y;
            }
        }
    }

    if (kg == 1) {
        #pragma unroll
        for (int b = 0; b < 32; ++b) red[cp][b] = acc[b];
    }
    __syncthreads();
    if (kg == 0) {
        const int ks = blockIdx.y;
        #pragma unroll
        for (int b = 0; b < 32; ++b) {
            float2 o = red[cp][b];
            float2 v; v.x = acc[b].x + o.x; v.y = acc[b].y + o.y;
            *(float2*)&P[((size_t)ks * 32 + b) * Ntot + nb + cp * 2] = v;
        }
    }
}

// ---------------------------------------------------------------------------
// Reduce 32 split-K partials for QKV + fused RoPE (+ 1/sqrt(128) on q).
// ---------------------------------------------------------------------------
__global__ __launch_bounds__(256) void reduce_rope(
    const float* __restrict__ P, const float* __restrict__ freqs,
    float* __restrict__ qkv)
{
    int t = blockIdx.x * 256 + threadIdx.x;   // 0..98303
    int b = t / 3072;
    int cp = t - b * 3072;
    int n = cp * 2;
    float sx = 0.f, sy = 0.f;
    #pragma unroll
    for (int ks = 0; ks < 32; ++ks) {
        float2 v = *(const float2*)&P[((size_t)ks * 32 + b) * 6144 + n];
        sx += v.x; sy += v.y;
    }
    if (n < 5120) {
        int d = n & 127;
        float fr = freqs[d >> 1];
        float c = cosf(fr), s = sinf(fr);
        float ra = sx * c - sy * s;
        float rb = sx * s + sy * c;
        if (n < 4096) {
            const float sc = 0.08838834764831845f;  // 1/sqrt(128)
            ra *= sc; rb *= sc;
        }
        sx = ra; sy = rb;
    }
    float2 o; o.x = sx; o.y = sy;
    *(float2*)&qkv[(size_t)b * 6144 + n] = o;
}

// ---------------------------------------------------------------------------
// Attention: one block per (b, kv). 1024 threads. (unchanged from round 2)
// ---------------------------------------------------------------------------
__global__ __launch_bounds__(1024) void attn_kernel(
    const float* __restrict__ qkv,
    const float* __restrict__ ck, const float* __restrict__ cv,
    float* __restrict__ ao)
{
    __shared__ float sbuf[8208];
    __shared__ float red[4][4];
    __shared__ float mxv[4];
    __shared__ float inv[4];

    const int b  = blockIdx.x >> 3;
    const int kv = blockIdx.x & 7;
    const int tid = threadIdx.x;
    const int wave = tid >> 6, lane = tid & 63;
    const int psub = (lane >> 4) & 3, dl = lane & 15;

    float q[4][8];
    {
        const float* qb = qkv + (size_t)b * 6144 + kv * 512 + dl * 8;
        #pragma unroll
        for (int h = 0; h < 4; ++h) {
            float4 a = *(const float4*)&qb[h * 128];
            float4 c = *(const float4*)&qb[h * 128 + 4];
            q[h][0]=a.x; q[h][1]=a.y; q[h][2]=a.z; q[h][3]=a.w;
            q[h][4]=c.x; q[h][5]=c.y; q[h][6]=c.z; q[h][7]=c.w;
        }
    }

    if (tid < 16) {
        const float* kr = qkv + (size_t)b * 6144 + 4096 + kv * 128 + dl * 8;
        float4 k0 = *(const float4*)kr;
        float4 k1 = *(const float4*)(kr + 4);
        float p[4];
        #pragma unroll
        for (int h = 0; h < 4; ++h) {
            p[h] = q[h][0]*k0.x + q[h][1]*k0.y + q[h][2]*k0.z + q[h][3]*k0.w
                 + q[h][4]*k1.x + q[h][5]*k1.y + q[h][6]*k1.z + q[h][7]*k1.w;
        }
        #pragma unroll
        for (int off = 1; off < 16; off <<= 1) {
            #pragma unroll
            for (int h = 0; h < 4; ++h) p[h] += __shfl_xor(p[h], off);
        }
        if (dl == 0) {
            #pragma unroll
            for (int h = 0; h < 4; ++h) sbuf[h * 2052 + 2048] = p[h];
        }
    }

    const float* kbase = ck + ((size_t)b * 2048 * 8 + kv) * 128;
    const int srow = wave * 4 + psub;
    for (int it0 = 0; it0 < 32; it0 += 4) {
        float4 kA[4][2];
        #pragma unroll
        for (int u = 0; u < 4; ++u) {
            const float* kr = kbase + (size_t)((it0 + u) * 64 + srow) * 1024 + dl * 8;
            kA[u][0] = *(const float4*)kr;
            kA[u][1] = *(const float4*)(kr + 4);
        }
        #pragma unroll
        for (int u = 0; u < 4; ++u) {
            int s = (it0 + u) * 64 + srow;
            float p[4];
            #pragma unroll
            for (int h = 0; h < 4; ++h) {
                p[h] = q[h][0]*kA[u][0].x + q[h][1]*kA[u][0].y
                     + q[h][2]*kA[u][0].z + q[h][3]*kA[u][0].w
                     + q[h][4]*kA[u][1].x + q[h][5]*kA[u][1].y
                     + q[h][6]*kA[u][1].z + q[h][7]*kA[u][1].w;
            }
            #pragma unroll
            for (int off = 1; off < 16; off <<= 1) {
                #pragma unroll
                for (int h = 0; h < 4; ++h) p[h] += __shfl_xor(p[h], off);
            }
            if (dl == 0) {
                #pragma unroll
                for (int h = 0; h < 4; ++h) sbuf[h * 2052 + s] = p[h];
            }
        }
    }
    __syncthreads();

    const int h = tid >> 8, r = tid & 255;
    float m = -1e30f;
    for (int s = r; s < 2049; s += 256) m = fmaxf(m, sbuf[h * 2052 + s]);
    #pragma unroll
    for (int off = 1; off < 64; off <<= 1) m = fmaxf(m, __shfl_xor(m, off));
    if (lane == 0) red[h][wave & 3] = m;
    __syncthreads();
    if (r == 0)
        mxv[h] = fmaxf(fmaxf(red[h][0], red[h][1]), fmaxf(red[h][2], red[h][3]));
    __syncthreads();
    const float mx = mxv[h];
    float sum = 0.f;
    for (int s = r; s < 2049; s += 256) {
        float p = __expf(sbuf[h * 2052 + s] - mx);
        sbuf[h * 2052 + s] = p;
        sum += p;
    }
    #pragma unroll
    for (int off = 1; off < 64; off <<= 1) sum += __shfl_xor(sum, off);
    if (lane == 0) red[h][wave & 3] = sum;
    __syncthreads();
    if (r == 0) inv[h] = 1.0f / (red[h][0] + red[h][1] + red[h][2] + red[h][3]);
    __syncthreads();

    const int grp = tid >> 5, l32 = tid & 31, d4 = l32 * 4;
    float4 acc[4];
    #pragma unroll
    for (int hh = 0; hh < 4; ++hh) { acc[hh].x=0.f; acc[hh].y=0.f; acc[hh].z=0.f; acc[hh].w=0.f; }
    const float* vbase = cv + ((size_t)b * 2048 * 8 + kv) * 128;
    for (int it = 0; it < 16; ++it) {
        float4 vv[4];
        float pp[4][4];
        #pragma unroll
        for (int j = 0; j < 4; ++j) {
            int s = it * 128 + j * 32 + grp;
            vv[j] = *(const float4*)&vbase[(size_t)s * 1024 + d4];
        }
        #pragma unroll
        for (int j = 0; j < 4; ++j) {
            int s = it * 128 + j * 32 + grp;
            #pragma unroll
            for (int hh = 0; hh < 4; ++hh) pp[j][hh] = sbuf[hh * 2052 + s];
        }
        #pragma unroll
        for (int j = 0; j < 4; ++j) {
            #pragma unroll
            for (int hh = 0; hh < 4; ++hh) {
                acc[hh].x += pp[j][hh] * vv[j].x;
                acc[hh].y += pp[j][hh] * vv[j].y;
                acc[hh].z += pp[j][hh] * vv[j].z;
                acc[hh].w += pp[j][hh] * vv[j].w;
            }
        }
    }
    if (grp == 0) {
        const float* vr = qkv + (size_t)b * 6144 + 5120 + kv * 128;
        float4 v = *(const float4*)&vr[d4];
        #pragma unroll
        for (int hh = 0; hh < 4; ++hh) {
            float p = sbuf[hh * 2052 + 2048];
            acc[hh].x += p * v.x; acc[hh].y += p * v.y;
            acc[hh].z += p * v.z; acc[hh].w += p * v.w;
        }
    }
    __syncthreads();

    #pragma unroll
    for (int hh = 0; hh < 4; ++hh) {
        acc[hh].x += __shfl_down(acc[hh].x, 32);
        acc[hh].y += __shfl_down(acc[hh].y, 32);
        acc[hh].z += __shfl_down(acc[hh].z, 32);
        acc[hh].w += __shfl_down(acc[hh].w, 32);
    }
    if (lane < 32) {
        #pragma unroll
        for (int hh = 0; hh < 4; ++hh)
            *(float4*)&sbuf[wave * 512 + hh * 128 + d4] = acc[hh];
    }
    __syncthreads();

    if (tid < 512) {
        int hh = tid >> 7, d = tid & 127;
        float v = 0.f;
        #pragma unroll
        for (int w = 0; w < 16; ++w) v += sbuf[w * 512 + hh * 128 + d];
        ao[(size_t)b * 4096 + kv * 512 + hh * 128 + d] = v * inv[hh];
    }
}

// ---------------------------------------------------------------------------
// Reduce 32 split-K partials for output projection -> d_out
// ---------------------------------------------------------------------------
__global__ __launch_bounds__(256) void reduce_out(
    const float* __restrict__ P, float* __restrict__ out)
{
    int t = blockIdx.x * 256 + threadIdx.x;   // float2 units
    int b = t >> 11;
    int cp = t & 2047;
    int n = cp * 2;
    float sx = 0.f, sy = 0.f;
    #pragma unroll
    for (int ks = 0; ks < 32; ++ks) {
        float2 v = *(const float2*)&P[((size_t)ks * 32 + b) * 4096 + n];
        sx += v.x; sy += v.y;
    }
    float2 o; o.x = sx; o.y = sy;
    *(float2*)&out[(size_t)b * 4096 + n] = o;
}

extern "C" void kernel_launch(void* const* d_in, const int* in_sizes, int n_in,
                              void* d_out, int out_size, void* d_ws, size_t ws_size,
                              hipStream_t stream) {
    const float* x  = (const float*)d_in[0];
    const float* wq = (const float*)d_in[1];
    const float* wk = (const float*)d_in[2];
    const float* wv = (const float*)d_in[3];
    const float* wo = (const float*)d_in[4];
    const float* ck = (const float*)d_in[5];
    const float* cv = (const float*)d_in[6];
    const float* fr = (const float*)d_in[7];
    float* out = (float*)d_out;
    float* ws  = (float*)d_ws;

    float* P1   = ws + WS_P1;
    float* qkv  = ws + WS_QKV;
    float* attn = ws + WS_ATTN;
    float* P2   = ws + WS_P2;

    dim3 g1(24, 32);
    gemm_skinny<<<g1, 256, 0, stream>>>(x, wq, 4096, 4096, wk, 5120, 1024,
                                        wv, 1024, P1, 6144);
    reduce_rope<<<384, 256, 0, stream>>>(P1, fr, qkv);
    attn_kernel<<<256, 1024, 0, stream>>>(qkv, ck, cv, attn);
    dim3 g4(16, 32);
    gemm_skinny<<<g4, 256, 0, stream>>>(attn, wo, 4096, 4096, wo, 4096, 4096,
                                        wo, 4096, P2, 4096);
    reduce_out<<<256, 256, 0, stream>>>(P2, out);
}

// Round 4
// 183.524 us; speedup vs baseline: 1.3914x; 1.0009x over previous
//
#include <hip/hip_runtime.h>

// Shapes: B=32, S_NEW=1, DIM=4096, H=32, KV=8, HD=128, PREV=2048, SEQ=2049
// All inputs/outputs fp32.
//
// ws layout (float offsets):
//   P1   [32][32][6144] @ 0        (6291456) qkv split-K partials
//   qkv  [32][6144]     @ 6291456  (196608)  rope'd q (scaled), k_new, v_new
//   attn [32][4096]     @ 6488064  (131072)  attention output (b, h, d)
//   P2   [32][32][4096] @ 6619136  (4194304) out-proj split-K partials
//   PA   [1024][520]    @ 10813440 (532480)  flash partials: m[4],l[4],o[4][128]

#define WS_P1   0
#define WS_QKV  6291456
#define WS_ATTN 6488064
#define WS_P2   6619136
#define WS_PA   10813440

// ---------------------------------------------------------------------------
// Skinny GEMM partial: P[ks][b][n] = sum_{k in 128-chunk} X[b][k] * W[k][n]
// grid: (Ntot/256, 32), block: 256 threads = 128 colpairs x 2 k-groups.
// ---------------------------------------------------------------------------
__global__ __launch_bounds__(256) void gemm_skinny(
    const float* __restrict__ X,
    const float* __restrict__ W0, int e0, int ld0,
    const float* __restrict__ W1, int e1, int ld1,
    const float* __restrict__ W2, int ld2,
    float* __restrict__ P, int Ntot)
{
    __shared__ float x_t[128][36];     // transposed x chunk [kk][b], pad 36
    __shared__ float2 red[128][33];    // 2-way kg reduce, pad 33

    const int nb = blockIdx.x * 256;
    const float* W; int ld, noff;
    if (nb < e0)      { W = W0; ld = ld0; noff = 0;  }
    else if (nb < e1) { W = W1; ld = ld1; noff = e0; }
    else              { W = W2; ld = ld2; noff = e1; }

    const int k0  = blockIdx.y * 128;
    const int tid = threadIdx.x;
    const int cp  = tid & 127;
    const int kg  = tid >> 7;
    const int nn  = nb - noff + cp * 2;

    #pragma unroll
    for (int i = 0; i < 16; ++i) {
        int idx = tid + i * 256;
        int bb = idx >> 7, kk = idx & 127;
        x_t[kk][bb] = X[(size_t)bb * 4096 + k0 + kk];
    }
    __syncthreads();

    float2 acc[32];
    #pragma unroll
    for (int b = 0; b < 32; ++b) { acc[b].x = 0.f; acc[b].y = 0.f; }

    const float* Wp = W + (size_t)k0 * ld + nn;
    for (int kk0 = kg * 64; kk0 < kg * 64 + 64; kk0 += 8) {
        float2 w[8];
        #pragma unroll
        for (int u = 0; u < 8; ++u)
            w[u] = *(const float2*)&Wp[(size_t)(kk0 + u) * ld];
        #pragma unroll
        for (int u = 0; u < 8; ++u) {
            const float* xr = x_t[kk0 + u];
            #pragma unroll
            for (int bq = 0; bq < 8; ++bq) {
                float4 xv = *(const float4*)&xr[bq * 4];
                acc[bq*4+0].x += xv.x * w[u].x; acc[bq*4+0].y += xv.x * w[u].y;
                acc[bq*4+1].x += xv.y * w[u].x; acc[bq*4+1].y += xv.y * w[u].y;
                acc[bq*4+2].x += xv.z * w[u].x; acc[bq*4+2].y += xv.z * w[u].y;
                acc[bq*4+3].x += xv.w * w[u].x; acc[bq*4+3].y += xv.w * w[u].y;
            }
        }
    }

    if (kg == 1) {
        #pragma unroll
        for (int b = 0; b < 32; ++b) red[cp][b] = acc[b];
    }
    __syncthreads();
    if (kg == 0) {
        const int ks = blockIdx.y;
        #pragma unroll
        for (int b = 0; b < 32; ++b) {
            float2 o = red[cp][b];
            float2 v; v.x = acc[b].x + o.x; v.y = acc[b].y + o.y;
            *(float2*)&P[((size_t)ks * 32 + b) * Ntot + nb + cp * 2] = v;
        }
    }
}

// ---------------------------------------------------------------------------
// Reduce 32 split-K partials for QKV + fused RoPE (+ 1/sqrt(128) on q).
// ---------------------------------------------------------------------------
__global__ __launch_bounds__(256) void reduce_rope(
    const float* __restrict__ P, const float* __restrict__ freqs,
    float* __restrict__ qkv)
{
    int t = blockIdx.x * 256 + threadIdx.x;
    int b = t / 3072;
    int cp = t - b * 3072;
    int n = cp * 2;
    float sx = 0.f, sy = 0.f;
    #pragma unroll
    for (int ks = 0; ks < 32; ++ks) {
        float2 v = *(const float2*)&P[((size_t)ks * 32 + b) * 6144 + n];
        sx += v.x; sy += v.y;
    }
    if (n < 5120) {
        int d = n & 127;
        float fr = freqs[d >> 1];
        float c = cosf(fr), s = sinf(fr);
        float ra = sx * c - sy * s;
        float rb = sx * s + sy * c;
        if (n < 4096) {
            const float sc = 0.08838834764831845f;  // 1/sqrt(128)
            ra *= sc; rb *= sc;
        }
        sx = ra; sy = rb;
    }
    float2 o; o.x = sx; o.y = sy;
    *(float2*)&qkv[(size_t)b * 6144 + n] = o;
}

// ---------------------------------------------------------------------------
// Flash-decode split-S attention. grid 1024 = (b, kv, chunk c of 512 rows),
// block 256 (4 waves). Emits per-chunk m[4], l[4], unnormalized o[4][128].
// Chunk 3 additionally handles the new token (row 2048).
// ---------------------------------------------------------------------------
__global__ __launch_bounds__(256, 4) void attn_split(
    const float* __restrict__ qkv,
    const float* __restrict__ ck, const float* __restrict__ cv,
    float* __restrict__ pa)
{
    __shared__ float sbuf[4096];   // sc[4][520] (2080) then op[8][512] (4096)
    __shared__ float pm[4], pl[4];

    const int blk = blockIdx.x;
    const int c   = blk & 3;
    const int kv  = (blk >> 2) & 7;
    const int b   = blk >> 5;
    const int tid = threadIdx.x;
    const int wave = tid >> 6, lane = tid & 63;
    const int psub = (lane >> 4) & 3, dl = lane & 15;
    const int s0 = c * 512;

    // q fragments: 4 heads x this lane's 8-dim slice (pre-scaled)
    float q[4][8];
    {
        const float* qb = qkv + (size_t)b * 6144 + kv * 512 + dl * 8;
        #pragma unroll
        for (int h = 0; h < 4; ++h) {
            float4 a = *(const float4*)&qb[h * 128];
            float4 e = *(const float4*)&qb[h * 128 + 4];
            q[h][0]=a.x; q[h][1]=a.y; q[h][2]=a.z; q[h][3]=a.w;
            q[h][4]=e.x; q[h][5]=e.y; q[h][6]=e.z; q[h][7]=e.w;
        }
    }

    // new-token score (chunk 3 only), lanes 0..15
    if (c == 3 && tid < 16) {
        const float* kr = qkv + (size_t)b * 6144 + 4096 + kv * 128 + dl * 8;
        float4 k0 = *(const float4*)kr;
        float4 k1 = *(const float4*)(kr + 4);
        float p[4];
        #pragma unroll
        for (int h = 0; h < 4; ++h) {
            p[h] = q[h][0]*k0.x + q[h][1]*k0.y + q[h][2]*k0.z + q[h][3]*k0.w
                 + q[h][4]*k1.x + q[h][5]*k1.y + q[h][6]*k1.z + q[h][7]*k1.w;
        }
        #pragma unroll
        for (int off = 1; off < 16; off <<= 1) {
            #pragma unroll
            for (int h = 0; h < 4; ++h) p[h] += __shfl_xor(p[h], off);
        }
        if (dl == 0) {
            #pragma unroll
            for (int h = 0; h < 4; ++h) sbuf[h * 520 + 512] = p[h];
        }
    }

    // phase 1: scores for this chunk's 512 rows, 4-deep batching
    const float* kbase = ck + ((size_t)b * 2048 * 8 + kv) * 128
                            + (size_t)s0 * 1024;
    const int srow = wave * 4 + psub;       // 0..15
    for (int it0 = 0; it0 < 32; it0 += 4) {
        float4 kA[4][2];
        #pragma unroll
        for (int u = 0; u < 4; ++u) {
            const float* kr = kbase + (size_t)((it0 + u) * 16 + srow) * 1024 + dl * 8;
            kA[u][0] = *(const float4*)kr;
            kA[u][1] = *(const float4*)(kr + 4);
        }
        #pragma unroll
        for (int u = 0; u < 4; ++u) {
            int s = (it0 + u) * 16 + srow;
            float p[4];
            #pragma unroll
            for (int h = 0; h < 4; ++h) {
                p[h] = q[h][0]*kA[u][0].x + q[h][1]*kA[u][0].y
                     + q[h][2]*kA[u][0].z + q[h][3]*kA[u][0].w
                     + q[h][4]*kA[u][1].x + q[h][5]*kA[u][1].y
                     + q[h][6]*kA[u][1].z + q[h][7]*kA[u][1].w;
            }
            #pragma unroll
            for (int off = 1; off < 16; off <<= 1) {
                #pragma unroll
                for (int h = 0; h < 4; ++h) p[h] += __shfl_xor(p[h], off);
            }
            if (dl == 0) {
                #pragma unroll
                for (int h = 0; h < 4; ++h) sbuf[h * 520 + s] = p[h];
            }
        }
    }
    __syncthreads();

    // partial softmax: wave w owns head w (64 lanes over 512/513 entries)
    {
        const int h = wave;
        const int nrow = (c == 3) ? 513 : 512;
        float m = -1e30f;
        for (int s = lane; s < nrow; s += 64) m = fmaxf(m, sbuf[h * 520 + s]);
        #pragma unroll
        for (int off = 1; off < 64; off <<= 1) m = fmaxf(m, __shfl_xor(m, off));
        float sum = 0.f;
        for (int s = lane; s < nrow; s += 64) {
            float p = __expf(sbuf[h * 520 + s] - m);
            sbuf[h * 520 + s] = p;
            sum += p;
        }
        #pragma unroll
        for (int off = 1; off < 64; off <<= 1) sum += __shfl_xor(sum, off);
        if (lane == 0) { pm[h] = m; pl[h] = sum; }
    }
    __syncthreads();

    // phase 2: o_partial = P @ V over this chunk, 4-deep batching
    const int grp = tid >> 5, l32 = tid & 31, d4 = l32 * 4;
    float4 acc[4];
    #pragma unroll
    for (int hh = 0; hh < 4; ++hh) { acc[hh].x=0.f; acc[hh].y=0.f; acc[hh].z=0.f; acc[hh].w=0.f; }
    const float* vbase = cv + ((size_t)b * 2048 * 8 + kv) * 128
                            + (size_t)s0 * 1024;
    for (int it = 0; it < 16; ++it) {
        float4 vv[4];
        float pp[4][4];
        #pragma unroll
        for (int j = 0; j < 4; ++j) {
            int s = it * 32 + j * 8 + grp;
            vv[j] = *(const float4*)&vbase[(size_t)s * 1024 + d4];
        }
        #pragma unroll
        for (int j = 0; j < 4; ++j) {
            int s = it * 32 + j * 8 + grp;
            #pragma unroll
            for (int hh = 0; hh < 4; ++hh) pp[j][hh] = sbuf[hh * 520 + s];
        }
        #pragma unroll
        for (int j = 0; j < 4; ++j) {
            #pragma unroll
            for (int hh = 0; hh < 4; ++hh) {
                acc[hh].x += pp[j][hh] * vv[j].x;
                acc[hh].y += pp[j][hh] * vv[j].y;
                acc[hh].z += pp[j][hh] * vv[j].z;
                acc[hh].w += pp[j][hh] * vv[j].w;
            }
        }
    }
    if (c == 3 && grp == 0) {
        const float* vr = qkv + (size_t)b * 6144 + 5120 + kv * 128;
        float4 v = *(const float4*)&vr[d4];
        #pragma unroll
        for (int hh = 0; hh < 4; ++hh) {
            float p = sbuf[hh * 520 + 512];
            acc[hh].x += p * v.x; acc[hh].y += p * v.y;
            acc[hh].z += p * v.z; acc[hh].w += p * v.w;
        }
    }
    __syncthreads();   // sc reads done; sbuf becomes op[8][512]

    #pragma unroll
    for (int hh = 0; hh < 4; ++hh)
        *(float4*)&sbuf[grp * 512 + hh * 128 + d4] = acc[hh];
    __syncthreads();

    float* rec = pa + (size_t)blk * 520;
    for (int t = tid; t < 512; t += 256) {
        int hh = t >> 7, d = t & 127;
        float v = 0.f;
        #pragma unroll
        for (int g = 0; g < 8; ++g) v += sbuf[g * 512 + hh * 128 + d];
        rec[8 + hh * 128 + d] = v;
    }
    if (tid < 4) { rec[tid] = pm[tid]; rec[4 + tid] = pl[tid]; }
}

// ---------------------------------------------------------------------------
// Combine 4 flash partials per (b,kv): rescale by exp(m_c - M), normalize.
// grid 256 = (b*8+kv), block 128 (= d).
// ---------------------------------------------------------------------------
__global__ __launch_bounds__(128) void attn_combine(
    const float* __restrict__ pa, float* __restrict__ ao)
{
    __shared__ float w_[4][4];   // [c][h] = exp(m_c - M) / L
    const int g = blockIdx.x;
    const int d = threadIdx.x;
    const float* rec = pa + (size_t)g * 4 * 520;

    if (d < 4) {
        float m0 = rec[0*520 + d], m1 = rec[1*520 + d];
        float m2 = rec[2*520 + d], m3 = rec[3*520 + d];
        float M = fmaxf(fmaxf(m0, m1), fmaxf(m2, m3));
        float e0 = __expf(m0 - M), e1 = __expf(m1 - M);
        float e2 = __expf(m2 - M), e3 = __expf(m3 - M);
        float L = rec[0*520 + 4 + d] * e0 + rec[1*520 + 4 + d] * e1
                + rec[2*520 + 4 + d] * e2 + rec[3*520 + 4 + d] * e3;
        float inv = 1.0f / L;
        w_[0][d] = e0 * inv; w_[1][d] = e1 * inv;
        w_[2][d] = e2 * inv; w_[3][d] = e3 * inv;
    }
    __syncthreads();

    #pragma unroll
    for (int h = 0; h < 4; ++h) {
        float v = 0.f;
        #pragma unroll
        for (int c = 0; c < 4; ++c)
            v += rec[c*520 + 8 + h*128 + d] * w_[c][h];
        ao[(size_t)g * 512 + h * 128 + d] = v;
    }
}

// ---------------------------------------------------------------------------
// Reduce 32 split-K partials for output projection -> d_out
// ---------------------------------------------------------------------------
__global__ __launch_bounds__(256) void reduce_out(
    const float* __restrict__ P, float* __restrict__ out)
{
    int t = blockIdx.x * 256 + threadIdx.x;
    int b = t >> 11;
    int cp = t & 2047;
    int n = cp * 2;
    float sx = 0.f, sy = 0.f;
    #pragma unroll
    for (int ks = 0; ks < 32; ++ks) {
        float2 v = *(const float2*)&P[((size_t)ks * 32 + b) * 4096 + n];
        sx += v.x; sy += v.y;
    }
    float2 o; o.x = sx; o.y = sy;
    *(float2*)&out[(size_t)b * 4096 + n] = o;
}

extern "C" void kernel_launch(void* const* d_in, const int* in_sizes, int n_in,
                              void* d_out, int out_size, void* d_ws, size_t ws_size,
                              hipStream_t stream) {
    const float* x  = (const float*)d_in[0];
    const float* wq = (const float*)d_in[1];
    const float* wk = (const float*)d_in[2];
    const float* wv = (const float*)d_in[3];
    const float* wo = (const float*)d_in[4];
    const float* ck = (const float*)d_in[5];
    const float* cv = (const float*)d_in[6];
    const float* fr = (const float*)d_in[7];
    float* out = (float*)d_out;
    float* ws  = (float*)d_ws;

    float* P1   = ws + WS_P1;
    float* qkv  = ws + WS_QKV;
    float* attn = ws + WS_ATTN;
    float* P2   = ws + WS_P2;
    float* PA   = ws + WS_PA;

    dim3 g1(24, 32);
    gemm_skinny<<<g1, 256, 0, stream>>>(x, wq, 4096, 4096, wk, 5120, 1024,
                                        wv, 1024, P1, 6144);
    reduce_rope<<<384, 256, 0, stream>>>(P1, fr, qkv);
    attn_split<<<1024, 256, 0, stream>>>(qkv, ck, cv, PA);
    attn_combine<<<256, 128, 0, stream>>>(PA, attn);
    dim3 g4(16, 32);
    gemm_skinny<<<g4, 256, 0, stream>>>(attn, wo, 4096, 4096, wo, 4096, 4096,
                                        wo, 4096, P2, 4096);
    reduce_out<<<256, 256, 0, stream>>>(P2, out);
}